// Round 7
// baseline (249.980 us; speedup 1.0000x reference)
//
#include <hip/hip_runtime.h>

#define NN 50000
#define EE 1600000
#define CC 128
#define HH 8
#define TOT (EE + NN)               // 1,650,000 output rows
#define RPB 64                      // rows per bucket
#define NB  ((NN + RPB - 1) / RPB)  // 782 buckets
#define BCH 4096                    // edges per binning block
#define NBB ((EE + BCH - 1) / BCH)  // 391 binning blocks
#define MST 9                       // padded LDS stride (gcd(9,32)=1)

// ---- monotone float<->uint mapping for atomic max on floats ----
__device__ inline unsigned fflip(float f) {
    unsigned u = __float_as_uint(f);
    return (u & 0x80000000u) ? ~u : (u | 0x80000000u);
}
__device__ inline float funflip(unsigned u) {
    unsigned b = (u & 0x80000000u) ? (u ^ 0x80000000u) : ~u;
    return __uint_as_float(b);
}

// leaky_relu(z,0.2)*100
__device__ inline float act(float z) {
    z = (z >= 0.f) ? z : 0.2f * z;
    return z * 100.f;
}

// ---- y1b = x @ W[:C] + b, y2 = x @ W[C:]  (N x 8 each) ----
__global__ __launch_bounds__(256) void k_proj(const float* __restrict__ x,
                                              const float* __restrict__ W,
                                              const float* __restrict__ bias,
                                              float* __restrict__ y1b,
                                              float* __restrict__ y2) {
    __shared__ float w[2 * CC * HH];  // 2048 floats
    int tid = threadIdx.x;
    for (int i = tid; i < 2 * CC * HH; i += 256) w[i] = W[i];
    __syncthreads();
    int node = blockIdx.x * 16 + (tid >> 4);
    int j = tid & 15;
    if (node >= NN) return;
    int wofs = (j < 8) ? j : (CC * HH + j - 8);
    const float4* xv = (const float4*)(x + (size_t)node * CC);
    float acc = 0.f;
#pragma unroll 4
    for (int k4 = 0; k4 < CC / 4; ++k4) {
        float4 xx = xv[k4];
        int base = k4 * 32 + wofs;
        acc += xx.x * w[base];
        acc += xx.y * w[base + 8];
        acc += xx.z * w[base + 16];
        acc += xx.w * w[base + 24];
    }
    if (j < 8) y1b[(size_t)node * 8 + j] = acc + bias[j];
    else       y2[(size_t)node * 8 + (j - 8)] = acc;
}

// ---- bucket histogram: LDS-aggregated ----
__global__ __launch_bounds__(1024) void k_hist(const int* __restrict__ rowp,
                                               int* __restrict__ gcnt) {
    __shared__ int h[NB];
    int t = threadIdx.x;
    for (int i = t; i < NB; i += 1024) h[i] = 0;
    __syncthreads();
    int base = blockIdx.x * BCH;
    int n = EE - base; if (n > BCH) n = BCH;
    for (int i = t; i < n; i += 1024)
        atomicAdd(&h[rowp[base + i] >> 6], 1);
    __syncthreads();
    for (int i = t; i < NB; i += 1024)
        if (h[i]) atomicAdd(&gcnt[i], h[i]);
}

// ---- scan of NB bucket counts -> gbase[NB+1], gcur copy ----
__global__ __launch_bounds__(1024) void k_scanb(const int* __restrict__ gcnt,
                                                int* __restrict__ gbase,
                                                int* __restrict__ gcur) {
    __shared__ int p[1024];
    int t = threadIdx.x;
    int own = (t < NB) ? gcnt[t] : 0;
    p[t] = own;
    __syncthreads();
    for (int off = 1; off < 1024; off <<= 1) {
        int v = (t >= off) ? p[t - off] : 0;
        __syncthreads();
        p[t] += v;
        __syncthreads();
    }
    if (t < NB) {
        int ex = p[t] - own;
        gbase[t] = ex;
        gcur[t] = ex;
    }
    if (t == NB - 1) gbase[NB] = p[t];
}

// ---- binning: pack (rloc | c<<6 | bkt<<22, |ea|), coalesced flush ----
__global__ __launch_bounds__(1024) void k_bin(const int* __restrict__ rowp,
                                              const int* __restrict__ colp,
                                              const float* __restrict__ ea,
                                              int* __restrict__ gcur,
                                              uint2* __restrict__ pay) {
    __shared__ int hist[NB];
    __shared__ int lscan[NB];
    __shared__ int lofs[NB];
    __shared__ int gofs[NB];
    __shared__ int sc[1024];
    __shared__ uint2 stage[BCH];   // 32 KB
    int t = threadIdx.x;
    int base = blockIdx.x * BCH;
    int n = EE - base; if (n > BCH) n = BCH;
    for (int i = t; i < NB; i += 1024) hist[i] = 0;
    __syncthreads();
    for (int i = t; i < n; i += 1024)
        atomicAdd(&hist[rowp[base + i] >> 6], 1);
    __syncthreads();
    int own = (t < NB) ? hist[t] : 0;
    sc[t] = own;
    __syncthreads();
    for (int off = 1; off < 1024; off <<= 1) {
        int v = (t >= off) ? sc[t - off] : 0;
        __syncthreads();
        sc[t] += v;
        __syncthreads();
    }
    if (t < NB) {
        int ex = sc[t] - own;
        lscan[t] = ex;
        lofs[t] = ex;
        gofs[t] = own ? atomicAdd(&gcur[t], own) : 0;
    }
    __syncthreads();
    // place packed payload into stage, grouped by bucket
    for (int i = t; i < n; i += 1024) {
        int r = rowp[base + i];
        int c = colp[base + i];
        float w = fabsf(ea[base + i]);
        int bkt = r >> 6;
        int p = atomicAdd(&lofs[bkt], 1);
        stage[p] = make_uint2((unsigned)(r & 63) | ((unsigned)c << 6) |
                              ((unsigned)bkt << 22),
                              __float_as_uint(w));
    }
    __syncthreads();
    // flush: consecutive staged slots of a bucket -> consecutive global slots
    for (int i = t; i < n; i += 1024) {
        uint2 v = stage[i];
        int bkt = v.x >> 22;
        pay[gofs[bkt] + (i - lscan[bkt])] = v;
    }
}

// ---- slot-parallel logit materialization (8 lanes/edge, coalesced write) ----
__global__ __launch_bounds__(256) void k_alpha(const uint2* __restrict__ pay,
                                               const float* __restrict__ y1b,
                                               const float* __restrict__ y2,
                                               float* __restrict__ pal) {
    int g = blockIdx.x * 32 + (threadIdx.x >> 3);
    int h = threadIdx.x & 7;
    if (g >= EE) return;
    uint2 p = pay[g];
    int rloc = p.x & 63;
    int c = (p.x >> 6) & 0xFFFF;
    int bkt = p.x >> 22;
    int r = bkt * RPB + rloc;
    float w = __uint_as_float(p.y);
    float a = act((y1b[(size_t)r * 8 + h] + y2[(size_t)c * 8 + h]) * w);
    pal[(size_t)g * 8 + h] = a;
}

// ---- per-bucket segment max+sum: pure streaming + LDS atomics ----
// 256-thread blocks, tiny LDS -> high occupancy for latency hiding
__global__ __launch_bounds__(256) void k_ms(const int* __restrict__ gbase,
                                            const uint2* __restrict__ pay,
                                            const float* __restrict__ pal,
                                            const float* __restrict__ y1b,
                                            const float* __restrict__ y2,
                                            float2* __restrict__ ms) {
    __shared__ unsigned mloc[RPB * MST];  // 2.3 KB
    __shared__ float    sloc[RPB * MST];  // 2.3 KB
    int b = blockIdx.x;
    int r0 = b * RPB;
    int nr = NN - r0; if (nr > RPB) nr = RPB;
    int t = threadIdx.x;
    // init with self-loop alpha (always present -> no -inf handling)
    for (int i = t; i < nr * HH; i += 256) {
        int rr = i >> 3, h = i & 7;
        float a = act(y1b[(size_t)r0 * 8 + i] + y2[(size_t)r0 * 8 + i]);  // w=1
        int idx = rr * MST + h;
        mloc[idx] = fflip(a);
        sloc[idx] = a;                 // stash self logit
    }
    __syncthreads();
    int s0 = gbase[b], s1 = gbase[b + 1];
    int h = t & 7;
    int eo = t >> 3;                   // 0..31
    // sweep a: max (coalesced pal stream)
    for (int i = s0 + eo; i < s1; i += 32) {
        float a = pal[(size_t)i * 8 + h];
        int rloc = pay[i].x & 63;
        atomicMax(&mloc[rloc * MST + h], fflip(a));
    }
    __syncthreads();
    // convert self stash -> s init = exp(a_self - m)
    for (int i = t; i < nr * HH; i += 256) {
        int idx = (i >> 3) * MST + (i & 7);
        sloc[idx] = __expf(sloc[idx] - funflip(mloc[idx]));
    }
    __syncthreads();
    // sweep b: sum of exp (coalesced pal stream)
    for (int i = s0 + eo; i < s1; i += 32) {
        float a = pal[(size_t)i * 8 + h];
        int rloc = pay[i].x & 63;
        int idx = rloc * MST + h;
        atomicAdd(&sloc[idx], __expf(a - funflip(mloc[idx])));
    }
    __syncthreads();
    for (int i = t; i < nr * HH; i += 256) {
        int idx = (i >> 3) * MST + (i & 7);
        ms[(size_t)r0 * 8 + i] = make_float2(funflip(mloc[idx]), sloc[idx]);
    }
}

// ---- finalize: 8 lanes per output row; overwrites pal region ----
__global__ __launch_bounds__(256) void k_final(const int* __restrict__ rowp,
                                               const int* __restrict__ colp,
                                               const float* __restrict__ ea,
                                               const float* __restrict__ y1b,
                                               const float* __restrict__ y2,
                                               const float2* __restrict__ ms,
                                               float* __restrict__ alpha,
                                               float* __restrict__ oidx) {
    long long g = (long long)blockIdx.x * 256 + threadIdx.x;
    int e = (int)(g >> 3);
    int h = (int)(g & 7);
    if (e >= TOT) return;
    int r, c; float w;
    if (e < EE) { r = rowp[e]; c = colp[e]; w = fabsf(ea[e]); }
    else        { r = e - EE;  c = r;       w = 1.0f; }
    float a = act((y1b[(size_t)r * 8 + h] + y2[(size_t)c * 8 + h]) * w);
    float2 msv = ms[(size_t)r * 8 + h];
    alpha[(size_t)e * 8 + h] = __expf(a - msv.x) / (msv.y + 1e-16f);
    if (h == 0) oidx[e] = (float)r;
    if (h == 1) oidx[(size_t)TOT + e] = (float)c;
}

extern "C" void kernel_launch(void* const* d_in, const int* in_sizes, int n_in,
                              void* d_out, int out_size, void* d_ws, size_t ws_size,
                              hipStream_t stream) {
    const float* x    = (const float*)d_in[0];
    const int*   rowp = (const int*)d_in[1];          // edge_index[0]
    const int*   colp = rowp + EE;                    // edge_index[1]
    const float* ea   = (const float*)d_in[2];
    const float* W    = (const float*)d_in[3];
    const float* bias = (const float*)d_in[4];

    float* out_alpha = (float*)d_out;                 // [TOT][8]
    float* out_idx   = out_alpha + (size_t)TOT * 8;   // [2][TOT] as float

    // pal (binned logits, EE*8 floats = 51.2MB) lives in the out_alpha
    // region: fully consumed by k_ms before k_final overwrites it.
    float* pal = out_alpha;

    // workspace layout
    float*  y1b   = (float*)d_ws;                     // NN*8
    float*  y2    = y1b + (size_t)NN * 8;             // NN*8
    float2* ms    = (float2*)(y2 + (size_t)NN * 8);   // NN*8 float2
    uint2*  pay   = (uint2*)(ms + (size_t)NN * 8);    // EE uint2 (12.8 MB)
    int*    gcnt  = (int*)(pay + (size_t)EE);         // NB
    int*    gbase = gcnt + NB;                        // NB+1
    int*    gcur  = gbase + NB + 1;                   // NB

    hipMemsetAsync(gcnt, 0, NB * sizeof(int), stream);
    k_proj<<<(NN * 16 + 255) / 256, 256, 0, stream>>>(x, W, bias, y1b, y2);
    k_hist<<<NBB, 1024, 0, stream>>>(rowp, gcnt);
    k_scanb<<<1, 1024, 0, stream>>>(gcnt, gbase, gcur);
    k_bin<<<NBB, 1024, 0, stream>>>(rowp, colp, ea, gcur, pay);
    k_alpha<<<(EE + 31) / 32, 256, 0, stream>>>(pay, y1b, y2, pal);
    k_ms<<<NB, 256, 0, stream>>>(gbase, pay, pal, y1b, y2, ms);
    long long fin_threads = (long long)TOT * 8;
    int fin_blocks = (int)((fin_threads + 255) / 256);
    k_final<<<fin_blocks, 256, 0, stream>>>(rowp, colp, ea, y1b, y2, ms,
                                            out_alpha, out_idx);
}

// Round 8
// 147.475 us; speedup vs baseline: 1.6951x; 1.6951x over previous
//
#include <hip/hip_runtime.h>

#define NN 50000
#define EE 1600000
#define CC 128
#define HH 8
#define TOT (EE + NN)               // 1,650,000 output rows
#define RPB 64                      // rows per bucket
#define NB  ((NN + RPB - 1) / RPB)  // 782 buckets
#define BCH 4096                    // edges per binning block
#define NBB ((EE + BCH - 1) / BCH)  // 391 binning blocks
#define SCAP 3584                   // sort stage capacity (mean 2048, 34-sigma safe)
#define NIT 8                       // cached iterations (tot<=64; mean 33, max ~58)

// leaky_relu(z,0.2)*100
__device__ inline float act(float z) {
    z = (z >= 0.f) ? z : 0.2f * z;
    return z * 100.f;
}

// ---- y1b = x @ W[:C] + b, y2 = x @ W[C:]  (N x 8 each) ----
__global__ __launch_bounds__(256) void k_proj(const float* __restrict__ x,
                                              const float* __restrict__ W,
                                              const float* __restrict__ bias,
                                              float* __restrict__ y1b,
                                              float* __restrict__ y2) {
    __shared__ float w[2 * CC * HH];  // 2048 floats
    int tid = threadIdx.x;
    for (int i = tid; i < 2 * CC * HH; i += 256) w[i] = W[i];
    __syncthreads();
    int node = blockIdx.x * 16 + (tid >> 4);
    int j = tid & 15;
    if (node >= NN) return;
    int wofs = (j < 8) ? j : (CC * HH + j - 8);
    const float4* xv = (const float4*)(x + (size_t)node * CC);
    float acc = 0.f;
#pragma unroll 4
    for (int k4 = 0; k4 < CC / 4; ++k4) {
        float4 xx = xv[k4];
        int base = k4 * 32 + wofs;
        acc += xx.x * w[base];
        acc += xx.y * w[base + 8];
        acc += xx.z * w[base + 16];
        acc += xx.w * w[base + 24];
    }
    if (j < 8) y1b[(size_t)node * 8 + j] = acc + bias[j];
    else       y2[(size_t)node * 8 + (j - 8)] = acc;
}

// ---- bucket histogram: LDS-aggregated ----
__global__ __launch_bounds__(1024) void k_hist(const int* __restrict__ rowp,
                                               int* __restrict__ gcnt) {
    __shared__ int h[NB];
    int t = threadIdx.x;
    for (int i = t; i < NB; i += 1024) h[i] = 0;
    __syncthreads();
    int base = blockIdx.x * BCH;
    int n = EE - base; if (n > BCH) n = BCH;
    for (int i = t; i < n; i += 1024)
        atomicAdd(&h[rowp[base + i] >> 6], 1);
    __syncthreads();
    for (int i = t; i < NB; i += 1024)
        if (h[i]) atomicAdd(&gcnt[i], h[i]);
}

// ---- scan of NB bucket counts -> gbase[NB+1], gcur copy; rstart[NN]=EE ----
__global__ __launch_bounds__(1024) void k_scanb(const int* __restrict__ gcnt,
                                                int* __restrict__ gbase,
                                                int* __restrict__ gcur,
                                                int* __restrict__ rstart) {
    __shared__ int p[1024];
    int t = threadIdx.x;
    int own = (t < NB) ? gcnt[t] : 0;
    p[t] = own;
    __syncthreads();
    for (int off = 1; off < 1024; off <<= 1) {
        int v = (t >= off) ? p[t - off] : 0;
        __syncthreads();
        p[t] += v;
        __syncthreads();
    }
    if (t < NB) {
        int ex = p[t] - own;
        gbase[t] = ex;
        gcur[t] = ex;
    }
    if (t == NB - 1) gbase[NB] = p[t];
    if (t == 0) rstart[NN] = EE;
}

// ---- binning: pack (rloc | c<<6 | bkt<<22, |ea|), coalesced flush ----
__global__ __launch_bounds__(1024) void k_bin(const int* __restrict__ rowp,
                                              const int* __restrict__ colp,
                                              const float* __restrict__ ea,
                                              int* __restrict__ gcur,
                                              uint2* __restrict__ pay) {
    __shared__ int hist[NB];
    __shared__ int lscan[NB];
    __shared__ int lofs[NB];
    __shared__ int gofs[NB];
    __shared__ int sc[1024];
    __shared__ uint2 stage[BCH];   // 32 KB
    int t = threadIdx.x;
    int base = blockIdx.x * BCH;
    int n = EE - base; if (n > BCH) n = BCH;
    for (int i = t; i < NB; i += 1024) hist[i] = 0;
    __syncthreads();
    for (int i = t; i < n; i += 1024)
        atomicAdd(&hist[rowp[base + i] >> 6], 1);
    __syncthreads();
    int own = (t < NB) ? hist[t] : 0;
    sc[t] = own;
    __syncthreads();
    for (int off = 1; off < 1024; off <<= 1) {
        int v = (t >= off) ? sc[t - off] : 0;
        __syncthreads();
        sc[t] += v;
        __syncthreads();
    }
    if (t < NB) {
        int ex = sc[t] - own;
        lscan[t] = ex;
        lofs[t] = ex;
        gofs[t] = own ? atomicAdd(&gcur[t], own) : 0;
    }
    __syncthreads();
    // place packed payload into stage, grouped by bucket
    for (int i = t; i < n; i += 1024) {
        int r = rowp[base + i];
        int c = colp[base + i];
        float w = fabsf(ea[base + i]);
        int bkt = r >> 6;
        int p = atomicAdd(&lofs[bkt], 1);
        stage[p] = make_uint2((unsigned)(r & 63) | ((unsigned)c << 6) |
                              ((unsigned)bkt << 22),
                              __float_as_uint(w));
    }
    __syncthreads();
    // flush: consecutive staged slots of a bucket -> consecutive global slots
    for (int i = t; i < n; i += 1024) {
        uint2 v = stage[i];
        int bkt = v.x >> 22;
        pay[gofs[bkt] + (i - lscan[bkt])] = v;
    }
}

// ---- per-bucket counting sort by rloc -> row-sorted pay2=(c,w), rstart ----
__global__ __launch_bounds__(256) void k_sort(const int* __restrict__ gbase,
                                              const uint2* __restrict__ pay,
                                              uint2* __restrict__ pay2,
                                              int* __restrict__ rstart) {
    __shared__ int cnt[RPB];
    __shared__ int ofs2[RPB];
    __shared__ uint2 stg[SCAP];   // 28 KB
    int b = blockIdx.x;
    int s0 = gbase[b];
    int n = gbase[b + 1] - s0;
    int t = threadIdx.x;
    if (t < RPB) cnt[t] = 0;
    __syncthreads();
    for (int i = t; i < n; i += 256)
        atomicAdd(&cnt[pay[s0 + i].x & 63], 1);
    __syncthreads();
    if (t < RPB) {
        // inclusive shuffle scan over 64 lanes (wave 0 only, fully active)
        int v = cnt[t];
        int s = v;
        for (int off = 1; off < 64; off <<= 1) {
            int u = __shfl_up(s, off, 64);
            if (t >= off) s += u;
        }
        int ex = s - v;               // exclusive
        ofs2[t] = ex;
        int r0 = b * RPB;
        int nrows = NN - r0; if (nrows > RPB) nrows = RPB;
        if (t < nrows) rstart[r0 + t] = s0 + ex;
    }
    __syncthreads();
    for (int i = t; i < n; i += 256) {
        uint2 p = pay[s0 + i];
        int rl = p.x & 63;
        int pos = atomicAdd(&ofs2[rl], 1);
        stg[pos] = make_uint2((p.x >> 6) & 0xFFFF, p.y);
    }
    __syncthreads();
    for (int i = t; i < n; i += 256)
        pay2[s0 + i] = stg[i];
}

// ---- row-parallel softmax stats: one wave per row, registers only ----
__global__ __launch_bounds__(256) void k_row(const int* __restrict__ rstart,
                                             const uint2* __restrict__ pay2,
                                             const float* __restrict__ y1b,
                                             const float* __restrict__ y2,
                                             float2* __restrict__ ms) {
    int wv = threadIdx.x >> 6;
    int lane = threadIdx.x & 63;
    int r = blockIdx.x * 4 + wv;
    if (r >= NN) return;
    int sub = lane >> 3;   // edge slot within chunk (0..7)
    int h = lane & 7;      // head
    int s0 = rstart[r];
    int deg = rstart[r + 1] - s0;
    int tot = deg + 1;     // + self loop at slot == deg
    float yh = y1b[(size_t)r * 8 + h];
    float y2s = y2[(size_t)r * 8 + h];
    float cache[NIT];
    float mx = -__builtin_inff();
#pragma unroll
    for (int it = 0; it < NIT; ++it) {
        int i = it * 8 + sub;
        float a = -__builtin_inff();
        if (i < deg) {
            uint2 p = pay2[s0 + i];
            a = act((yh + y2[(size_t)p.x * 8 + h]) * __uint_as_float(p.y));
        } else if (i == deg) {
            a = act(yh + y2s);
        }
        cache[it] = a;
        mx = fmaxf(mx, a);
    }
    // rare tail (tot > 64)
    for (int i = NIT * 8 + sub; i < tot; i += 8) {
        float a;
        if (i < deg) {
            uint2 p = pay2[s0 + i];
            a = act((yh + y2[(size_t)p.x * 8 + h]) * __uint_as_float(p.y));
        } else {
            a = act(yh + y2s);
        }
        mx = fmaxf(mx, a);
    }
    mx = fmaxf(mx, __shfl_xor(mx, 8, 64));
    mx = fmaxf(mx, __shfl_xor(mx, 16, 64));
    mx = fmaxf(mx, __shfl_xor(mx, 32, 64));
    float sum = 0.f;
#pragma unroll
    for (int it = 0; it < NIT; ++it)
        sum += __expf(cache[it] - mx);   // exp(-inf) = 0 for empty slots
    for (int i = NIT * 8 + sub; i < tot; i += 8) {
        float a;
        if (i < deg) {
            uint2 p = pay2[s0 + i];
            a = act((yh + y2[(size_t)p.x * 8 + h]) * __uint_as_float(p.y));
        } else {
            a = act(yh + y2s);
        }
        sum += __expf(a - mx);
    }
    sum += __shfl_xor(sum, 8, 64);
    sum += __shfl_xor(sum, 16, 64);
    sum += __shfl_xor(sum, 32, 64);
    if (sub == 0) ms[(size_t)r * 8 + h] = make_float2(mx, sum);
}

// ---- finalize: 8 lanes per output row; overwrites pay2 region ----
__global__ __launch_bounds__(256) void k_final(const int* __restrict__ rowp,
                                               const int* __restrict__ colp,
                                               const float* __restrict__ ea,
                                               const float* __restrict__ y1b,
                                               const float* __restrict__ y2,
                                               const float2* __restrict__ ms,
                                               float* __restrict__ alpha,
                                               float* __restrict__ oidx) {
    long long g = (long long)blockIdx.x * 256 + threadIdx.x;
    int e = (int)(g >> 3);
    int h = (int)(g & 7);
    if (e >= TOT) return;
    int r, c; float w;
    if (e < EE) { r = rowp[e]; c = colp[e]; w = fabsf(ea[e]); }
    else        { r = e - EE;  c = r;       w = 1.0f; }
    float a = act((y1b[(size_t)r * 8 + h] + y2[(size_t)c * 8 + h]) * w);
    float2 msv = ms[(size_t)r * 8 + h];
    alpha[(size_t)e * 8 + h] = __expf(a - msv.x) / (msv.y + 1e-16f);
    if (h == 0) oidx[e] = (float)r;
    if (h == 1) oidx[(size_t)TOT + e] = (float)c;
}

extern "C" void kernel_launch(void* const* d_in, const int* in_sizes, int n_in,
                              void* d_out, int out_size, void* d_ws, size_t ws_size,
                              hipStream_t stream) {
    const float* x    = (const float*)d_in[0];
    const int*   rowp = (const int*)d_in[1];          // edge_index[0]
    const int*   colp = rowp + EE;                    // edge_index[1]
    const float* ea   = (const float*)d_in[2];
    const float* W    = (const float*)d_in[3];
    const float* bias = (const float*)d_in[4];

    float* out_alpha = (float*)d_out;                 // [TOT][8]
    float* out_idx   = out_alpha + (size_t)TOT * 8;   // [2][TOT] as float

    // pay2 (row-sorted payload, EE uint2 = 12.8MB) lives in the out_alpha
    // region: fully consumed by k_row before k_final overwrites it.
    uint2* pay2 = (uint2*)out_alpha;

    // workspace layout
    float*  y1b    = (float*)d_ws;                    // NN*8
    float*  y2     = y1b + (size_t)NN * 8;            // NN*8
    float2* ms     = (float2*)(y2 + (size_t)NN * 8);  // NN*8 float2
    uint2*  pay    = (uint2*)(ms + (size_t)NN * 8);   // EE uint2 (12.8 MB)
    int*    gcnt   = (int*)(pay + (size_t)EE);        // NB
    int*    gbase  = gcnt + NB;                       // NB+1
    int*    gcur   = gbase + NB + 1;                  // NB
    int*    rstart = gcur + NB;                       // NN+1

    hipMemsetAsync(gcnt, 0, NB * sizeof(int), stream);
    k_proj<<<(NN * 16 + 255) / 256, 256, 0, stream>>>(x, W, bias, y1b, y2);
    k_hist<<<NBB, 1024, 0, stream>>>(rowp, gcnt);
    k_scanb<<<1, 1024, 0, stream>>>(gcnt, gbase, gcur, rstart);
    k_bin<<<NBB, 1024, 0, stream>>>(rowp, colp, ea, gcur, pay);
    k_sort<<<NB, 256, 0, stream>>>(gbase, pay, pay2, rstart);
    k_row<<<(NN + 3) / 4, 256, 0, stream>>>(rstart, pay2, y1b, y2, ms);
    long long fin_threads = (long long)TOT * 8;
    int fin_blocks = (int)((fin_threads + 255) / 256);
    k_final<<<fin_blocks, 256, 0, stream>>>(rowp, colp, ea, y1b, y2, ms,
                                            out_alpha, out_idx);
}

// Round 9
// 135.498 us; speedup vs baseline: 1.8449x; 1.0884x over previous
//
#include <hip/hip_runtime.h>

#define NN 50000
#define EE 1600000
#define CC 128
#define HH 8
#define TOT (EE + NN)               // 1,650,000 output rows
#define RPB 64                      // rows per bucket
#define NB  ((NN + RPB - 1) / NN > 0 ? (NN + RPB - 1) / RPB : 1) // 782
#undef NB
#define NB  ((NN + RPB - 1) / RPB)  // 782 buckets
#define BCH 4096                    // edges per binning block
#define NBB ((EE + BCH - 1) / BCH)  // 391 binning blocks
#define SCAP 3584                   // sort stage capacity (mean 2048)
#define NIT 8                       // cached iterations (tot<=64 typical)

// leaky_relu(z,0.2)*100
__device__ inline float act(float z) {
    z = (z >= 0.f) ? z : 0.2f * z;
    return z * 100.f;
}

// ---- yk[r] = [x@W1 + b (8) | K placeholder (8)], y2 = x @ W[C:] ----
__global__ __launch_bounds__(256) void k_proj(const float* __restrict__ x,
                                              const float* __restrict__ W,
                                              const float* __restrict__ bias,
                                              float* __restrict__ yk,
                                              float* __restrict__ y2) {
    __shared__ float w[2 * CC * HH];  // 2048 floats
    int tid = threadIdx.x;
    for (int i = tid; i < 2 * CC * HH; i += 256) w[i] = W[i];
    __syncthreads();
    int node = blockIdx.x * 16 + (tid >> 4);
    int j = tid & 15;
    if (node >= NN) return;
    int wofs = (j < 8) ? j : (CC * HH + j - 8);
    const float4* xv = (const float4*)(x + (size_t)node * CC);
    float acc = 0.f;
#pragma unroll 4
    for (int k4 = 0; k4 < CC / 4; ++k4) {
        float4 xx = xv[k4];
        int base = k4 * 32 + wofs;
        acc += xx.x * w[base];
        acc += xx.y * w[base + 8];
        acc += xx.z * w[base + 16];
        acc += xx.w * w[base + 24];
    }
    if (j < 8) yk[(size_t)node * 16 + j] = acc + bias[j];
    else       y2[(size_t)node * 8 + (j - 8)] = acc;
}

// ---- bucket histogram: LDS-aggregated ----
__global__ __launch_bounds__(1024) void k_hist(const int* __restrict__ rowp,
                                               int* __restrict__ gcnt) {
    __shared__ int h[NB];
    int t = threadIdx.x;
    for (int i = t; i < NB; i += 1024) h[i] = 0;
    __syncthreads();
    int base = blockIdx.x * BCH;
    int n = EE - base; if (n > BCH) n = BCH;
    for (int i = t; i < n; i += 1024)
        atomicAdd(&h[rowp[base + i] >> 6], 1);
    __syncthreads();
    for (int i = t; i < NB; i += 1024)
        if (h[i]) atomicAdd(&gcnt[i], h[i]);
}

// ---- scan of NB bucket counts -> gbase[NB+1], gcur copy; rstart[NN]=EE ----
__global__ __launch_bounds__(1024) void k_scanb(const int* __restrict__ gcnt,
                                                int* __restrict__ gbase,
                                                int* __restrict__ gcur,
                                                int* __restrict__ rstart) {
    __shared__ int p[1024];
    int t = threadIdx.x;
    int own = (t < NB) ? gcnt[t] : 0;
    p[t] = own;
    __syncthreads();
    for (int off = 1; off < 1024; off <<= 1) {
        int v = (t >= off) ? p[t - off] : 0;
        __syncthreads();
        p[t] += v;
        __syncthreads();
    }
    if (t < NB) {
        int ex = p[t] - own;
        gbase[t] = ex;
        gcur[t] = ex;
    }
    if (t == NB - 1) gbase[NB] = p[t];
    if (t == 0) rstart[NN] = EE;
}

// ---- binning: pack (rloc | c<<6 | bkt<<22, |ea|), coalesced flush ----
__global__ __launch_bounds__(1024) void k_bin(const int* __restrict__ rowp,
                                              const int* __restrict__ colp,
                                              const float* __restrict__ ea,
                                              int* __restrict__ gcur,
                                              uint2* __restrict__ pay) {
    __shared__ int hist[NB];
    __shared__ int lscan[NB];
    __shared__ int lofs[NB];
    __shared__ int gofs[NB];
    __shared__ int sc[1024];
    __shared__ uint2 stage[BCH];   // 32 KB
    int t = threadIdx.x;
    int base = blockIdx.x * BCH;
    int n = EE - base; if (n > BCH) n = BCH;
    for (int i = t; i < NB; i += 1024) hist[i] = 0;
    __syncthreads();
    for (int i = t; i < n; i += 1024)
        atomicAdd(&hist[rowp[base + i] >> 6], 1);
    __syncthreads();
    int own = (t < NB) ? hist[t] : 0;
    sc[t] = own;
    __syncthreads();
    for (int off = 1; off < 1024; off <<= 1) {
        int v = (t >= off) ? sc[t - off] : 0;
        __syncthreads();
        sc[t] += v;
        __syncthreads();
    }
    if (t < NB) {
        int ex = sc[t] - own;
        lscan[t] = ex;
        lofs[t] = ex;
        gofs[t] = own ? atomicAdd(&gcur[t], own) : 0;
    }
    __syncthreads();
    for (int i = t; i < n; i += 1024) {
        int r = rowp[base + i];
        int c = colp[base + i];
        float w = fabsf(ea[base + i]);
        int bkt = r >> 6;
        int p = atomicAdd(&lofs[bkt], 1);
        stage[p] = make_uint2((unsigned)(r & 63) | ((unsigned)c << 6) |
                              ((unsigned)bkt << 22),
                              __float_as_uint(w));
    }
    __syncthreads();
    for (int i = t; i < n; i += 1024) {
        uint2 v = stage[i];
        int bkt = v.x >> 22;
        pay[gofs[bkt] + (i - lscan[bkt])] = v;
    }
}

// ---- per-bucket counting sort by rloc -> row-sorted pay2=(c,w), rstart ----
__global__ __launch_bounds__(256) void k_sort(const int* __restrict__ gbase,
                                              const uint2* __restrict__ pay,
                                              uint2* __restrict__ pay2,
                                              int* __restrict__ rstart) {
    __shared__ int cnt[RPB];
    __shared__ int ofs2[RPB];
    __shared__ uint2 stg[SCAP];   // 28 KB
    int b = blockIdx.x;
    int s0 = gbase[b];
    int n = gbase[b + 1] - s0;
    int t = threadIdx.x;
    if (t < RPB) cnt[t] = 0;
    __syncthreads();
    for (int i = t; i < n; i += 256)
        atomicAdd(&cnt[pay[s0 + i].x & 63], 1);
    __syncthreads();
    if (t < RPB) {
        int v = cnt[t];
        int s = v;
        for (int off = 1; off < 64; off <<= 1) {
            int u = __shfl_up(s, off, 64);
            if (t >= off) s += u;
        }
        int ex = s - v;               // exclusive
        ofs2[t] = ex;
        int r0 = b * RPB;
        int nrows = NN - r0; if (nrows > RPB) nrows = RPB;
        if (t < nrows) rstart[r0 + t] = s0 + ex;
    }
    __syncthreads();
    for (int i = t; i < n; i += 256) {
        uint2 p = pay[s0 + i];
        int rl = p.x & 63;
        int pos = atomicAdd(&ofs2[rl], 1);
        stg[pos] = make_uint2((p.x >> 6) & 0xFFFF, p.y);
    }
    __syncthreads();
    for (int i = t; i < n; i += 256)
        pay2[s0 + i] = stg[i];
}

// ---- row-parallel softmax stats: one wave per row -> K = m + log(s+eps) ----
__global__ __launch_bounds__(256) void k_row(const int* __restrict__ rstart,
                                             const uint2* __restrict__ pay2,
                                             float* __restrict__ yk,
                                             const float* __restrict__ y2) {
    int wv = threadIdx.x >> 6;
    int lane = threadIdx.x & 63;
    int r = blockIdx.x * 4 + wv;
    if (r >= NN) return;
    int sub = lane >> 3;   // edge slot within chunk (0..7)
    int h = lane & 7;      // head
    int s0 = rstart[r];
    int deg = rstart[r + 1] - s0;
    int tot = deg + 1;     // + self loop at slot == deg
    float yh = yk[(size_t)r * 16 + h];
    float y2s = y2[(size_t)r * 8 + h];
    float cache[NIT];
    float mx = -__builtin_inff();
#pragma unroll
    for (int it = 0; it < NIT; ++it) {
        int i = it * 8 + sub;
        float a = -__builtin_inff();
        if (i < deg) {
            uint2 p = pay2[s0 + i];
            a = act((yh + y2[(size_t)p.x * 8 + h]) * __uint_as_float(p.y));
        } else if (i == deg) {
            a = act(yh + y2s);
        }
        cache[it] = a;
        mx = fmaxf(mx, a);
    }
    for (int i = NIT * 8 + sub; i < tot; i += 8) {
        float a;
        if (i < deg) {
            uint2 p = pay2[s0 + i];
            a = act((yh + y2[(size_t)p.x * 8 + h]) * __uint_as_float(p.y));
        } else {
            a = act(yh + y2s);
        }
        mx = fmaxf(mx, a);
    }
    mx = fmaxf(mx, __shfl_xor(mx, 8, 64));
    mx = fmaxf(mx, __shfl_xor(mx, 16, 64));
    mx = fmaxf(mx, __shfl_xor(mx, 32, 64));
    float sum = 0.f;
#pragma unroll
    for (int it = 0; it < NIT; ++it)
        sum += __expf(cache[it] - mx);   // exp(-inf) = 0 for empty slots
    for (int i = NIT * 8 + sub; i < tot; i += 8) {
        float a;
        if (i < deg) {
            uint2 p = pay2[s0 + i];
            a = act((yh + y2[(size_t)p.x * 8 + h]) * __uint_as_float(p.y));
        } else {
            a = act(yh + y2s);
        }
        sum += __expf(a - mx);
    }
    sum += __shfl_xor(sum, 8, 64);
    sum += __shfl_xor(sum, 16, 64);
    sum += __shfl_xor(sum, 32, 64);
    if (sub == 0)
        yk[(size_t)r * 16 + 8 + h] = mx + __logf(sum + 1e-16f);
}

// ---- finalize: 8 lanes per output row; 2 gather-lines per edge ----
__global__ __launch_bounds__(256) void k_final(const int* __restrict__ rowp,
                                               const int* __restrict__ colp,
                                               const float* __restrict__ ea,
                                               const float* __restrict__ yk,
                                               const float* __restrict__ y2,
                                               float* __restrict__ alpha,
                                               float* __restrict__ oidx) {
    long long g = (long long)blockIdx.x * 256 + threadIdx.x;
    int e = (int)(g >> 3);
    int h = (int)(g & 7);
    if (e >= TOT) return;
    int r, c; float w;
    if (e < EE) { r = rowp[e]; c = colp[e]; w = fabsf(ea[e]); }
    else        { r = e - EE;  c = r;       w = 1.0f; }
    float yv = yk[(size_t)r * 16 + h];
    float Kv = yk[(size_t)r * 16 + 8 + h];
    float vb = y2[(size_t)c * 8 + h];
    float a = act((yv + vb) * w);
    float o = __expf(a - Kv);
    __builtin_nontemporal_store(o, &alpha[(size_t)e * 8 + h]);
    if (h == 0) __builtin_nontemporal_store((float)r, &oidx[e]);
    if (h == 1) __builtin_nontemporal_store((float)c, &oidx[(size_t)TOT + e]);
}

extern "C" void kernel_launch(void* const* d_in, const int* in_sizes, int n_in,
                              void* d_out, int out_size, void* d_ws, size_t ws_size,
                              hipStream_t stream) {
    const float* x    = (const float*)d_in[0];
    const int*   rowp = (const int*)d_in[1];          // edge_index[0]
    const int*   colp = rowp + EE;                    // edge_index[1]
    const float* ea   = (const float*)d_in[2];
    const float* W    = (const float*)d_in[3];
    const float* bias = (const float*)d_in[4];

    float* out_alpha = (float*)d_out;                 // [TOT][8]
    float* out_idx   = out_alpha + (size_t)TOT * 8;   // [2][TOT] as float

    // pay2 (row-sorted payload, EE uint2 = 12.8MB) lives in the out_alpha
    // region: fully consumed by k_row before k_final overwrites it.
    uint2* pay2 = (uint2*)out_alpha;

    // workspace layout
    float*  yk     = (float*)d_ws;                    // NN*16 (y1b | K), 64B/row
    float*  y2     = yk + (size_t)NN * 16;            // NN*8
    uint2*  pay    = (uint2*)(y2 + (size_t)NN * 8);   // EE uint2 (12.8 MB)
    int*    gcnt   = (int*)(pay + (size_t)EE);        // NB
    int*    gbase  = gcnt + NB;                       // NB+1
    int*    gcur   = gbase + NB + 1;                  // NB
    int*    rstart = gcur + NB;                       // NN+1

    hipMemsetAsync(gcnt, 0, NB * sizeof(int), stream);
    k_proj<<<(NN * 16 + 255) / 256, 256, 0, stream>>>(x, W, bias, yk, y2);
    k_hist<<<NBB, 1024, 0, stream>>>(rowp, gcnt);
    k_scanb<<<1, 1024, 0, stream>>>(gcnt, gbase, gcur, rstart);
    k_bin<<<NBB, 1024, 0, stream>>>(rowp, colp, ea, gcur, pay);
    k_sort<<<NB, 256, 0, stream>>>(gbase, pay, pay2, rstart);
    k_row<<<(NN + 3) / 4, 256, 0, stream>>>(rstart, pay2, yk, y2);
    long long fin_threads = (long long)TOT * 8;
    int fin_blocks = (int)((fin_threads + 255) / 256);
    k_final<<<fin_blocks, 256, 0, stream>>>(rowp, colp, ea, yk, y2,
                                            out_alpha, out_idx);
}